// Round 13
// baseline (210.813 us; speedup 1.0000x reference)
//
#include <hip/hip_runtime.h>
#include <hip/hip_bf16.h>

#define EPS_BN 1e-5f

typedef __attribute__((ext_vector_type(8))) short short8;   // 8 x bf16 (4 VGPR)
typedef __attribute__((ext_vector_type(4))) float float4v;  // MFMA acc

constexpr int NGROUPS    = 65536;     // B*P = 16*4096
constexpr int NEWX_ELEMS = 196608;    // B*P*3
constexpr int GRID       = 8192;      // 512-thr blocks, 8 waves, 1 group/wave

// d_ws layout: f32 indices for folded f32 data, byte offsets for bf16 weights
constexpr int W0F = 0;      // f32[192]  W0' (64x3)
constexpr int B0F = 192;    // f32[64]
constexpr int B1F = 256;    // f32[64]
constexpr int B2F = 320;    // f32[128]
constexpr int W1B = 1792;   // bytes: ushort[4096]  W1' (64x64) bf16
constexpr int W2B = 10240;  // bytes: ushort[8192]  W2' (128x64) bf16

__device__ __forceinline__ unsigned short f2bf(float x) {
    return __builtin_bit_cast(unsigned short, __float2bfloat16(x));
}
__device__ __forceinline__ unsigned cvtpk(float a, float b) {
    unsigned r;
    asm("v_cvt_pk_bf16_f32 %0, %1, %2" : "=v"(r) : "v"(a), "v"(b));
    return r;
}

__global__ void fold_kernel(
    const float* w0, const float* b0, const float* g0,
    const float* be0, const float* m0, const float* v0,
    const float* w1, const float* b1, const float* g1,
    const float* be1, const float* m1, const float* v1,
    const float* w2, const float* b2, const float* g2,
    const float* be2, const float* m2, const float* v2,
    float* __restrict__ ws)
{
    const int t = threadIdx.x;
    ushort* w1b = (ushort*)((char*)ws + W1B);
    ushort* w2b = (ushort*)((char*)ws + W2B);
    if (t < 64) {
        float s0 = g0[t] * rsqrtf(v0[t] + EPS_BN);
        ws[B0F + t] = (b0[t] - m0[t]) * s0 + be0[t];
        ws[W0F + t*3 + 0] = w0[t*3 + 0] * s0;
        ws[W0F + t*3 + 1] = w0[t*3 + 1] * s0;
        ws[W0F + t*3 + 2] = w0[t*3 + 2] * s0;
        float s1 = g1[t] * rsqrtf(v1[t] + EPS_BN);
        ws[B1F + t] = (b1[t] - m1[t]) * s1 + be1[t];
    }
    if (t < 128) {
        float s2 = g2[t] * rsqrtf(v2[t] + EPS_BN);
        ws[B2F + t] = (b2[t] - m2[t]) * s2 + be2[t];
    }
    for (int i = t; i < 64*64; i += 256) {
        int o = i >> 6;
        float s = g1[o] * rsqrtf(v1[o] + EPS_BN);
        w1b[i] = f2bf(w1[i] * s);
    }
    for (int i = t; i < 128*64; i += 256) {
        int o = i >> 6;
        float s = g2[o] * rsqrtf(v2[o] + EPS_BN);
        w2b[i] = f2bf(w2[i] * s);
    }
}

// new_x passthrough, f32 -> f32
__global__ void copy_new_x(const float4* __restrict__ in, float4* __restrict__ out)
{
    int i = blockIdx.x * 256 + threadIdx.x;   // < 49,152
    out[i] = in[i];
}

// SINGLE-VARIABLE occupancy experiment vs R12: identical per-group math
// (R9 path, 1 group/wave, straight-line), but 8-wave (512-thread) blocks:
// LDS = 16KB W2L (shared by 8 waves) + 8 x 4KB H = 48KB/block
//   -> 3 blocks/CU = 24 waves/CU = 6 waves/SIMD (vs 2.4-3 in R8-R12).
// lb(512,6) caps VGPR at 85 >= natural ~70 -> no spill (R5/R11 spilled at
// cap 64 with much larger live sets).
__global__ __launch_bounds__(512, 6) void sa_mfma_kernel(
    const float* __restrict__ xg,
    const float* __restrict__ wsf,
    float* __restrict__ feats)
{
    __shared__ __align__(16) ushort W2L[8192];      // 16KB swizzled W2'
    __shared__ __align__(16) ushort Hs[8][2048];    // 8 waves x 4KB

    const int tid = threadIdx.x;
    const int w   = tid >> 6;
    const int l   = tid & 63;
    const int l15 = l & 15;
    const int lhi = l >> 4;

    const ushort* w1b = (const ushort*)((const char*)wsf + W1B);
    const ushort* w2b = (const ushort*)((const char*)wsf + W2B);

    // ---- stage W2' into LDS (granule = 16B; gi = o*8 + c/8; dst = gi^(o&7))
    {
        const uint4* src = (const uint4*)w2b;   // 1024 granules
        uint4* dst = (uint4*)W2L;
        for (int gi = tid; gi < 1024; gi += 512)
            dst[gi ^ ((gi >> 3) & 7)] = src[gi];
    }

    ushort* H = Hs[w];
    const short8  zero8 = {0,0,0,0,0,0,0,0};
    const float4v zero4 = {0.f, 0.f, 0.f, 0.f};

    const int g = blockIdx.x * 8 + w;   // one group per wave

    // ---- x load (lanes lhi==0: sample = 16nt + l15) ----
    float xr[2][3];
#pragma unroll
    for (int nt = 0; nt < 2; ++nt)
        if (lhi == 0) {
            const float* xp = xg + ((size_t)g*32 + 16*nt + l15) * 3;
            xr[nt][0] = xp[0]; xr[nt][1] = xp[1]; xr[nt][2] = xp[2];
        }

    // ---- hoisted weight fragments ----
    short8 b0f[4];
#pragma unroll
    for (int mt = 0; mt < 4; ++mt) {
        union { short8 v; unsigned d[4]; } f;
        f.v = zero8;
        if (lhi == 0) {
            int o = 16*mt + l15;
            f.d[0] = cvtpk(wsf[W0F + o*3 + 0], wsf[W0F + o*3 + 1]);
            f.d[1] = cvtpk(wsf[W0F + o*3 + 2], wsf[B0F + o]);
        }
        b0f[mt] = f.v;
    }
    short8 b1f[2][4];
#pragma unroll
    for (int ks = 0; ks < 2; ++ks)
#pragma unroll
        for (int mt = 0; mt < 4; ++mt)
            b1f[ks][mt] = *(const short8*)&w1b[(16*mt + l15)*64 + 32*ks + 8*lhi];

    float4v b1vv[4];   // bias for h2 channels o = 16mt + 4lhi + i (acc layout)
#pragma unroll
    for (int mt = 0; mt < 4; ++mt)
        b1vv[mt] = *(const float4v*)&wsf[B1F + 16*mt + 4*lhi];
    float b2v[8];      // bias for output channels 16n + l15
#pragma unroll
    for (int n = 0; n < 8; ++n)
        b2v[n] = wsf[B2F + 16*n + l15];

    __syncthreads();   // W2L ready

    // ---- x fragments ----
    short8 xf[2];
#pragma unroll
    for (int nt = 0; nt < 2; ++nt) {
        union { short8 v; unsigned d[4]; } f;
        f.v = zero8;
        if (lhi == 0) {
            f.d[0] = cvtpk(xr[nt][0], xr[nt][1]);
            f.d[1] = cvtpk(xr[nt][2], 1.0f);
        }
        xf[nt] = f.v;
    }

    // ---- layer 0 (swapped): D[o][r]; relu; b64 writes -> H ----
#pragma unroll
    for (int nt = 0; nt < 2; ++nt) {
        const int r = 16*nt + l15;
        const int swz = (r & 7) << 3;
#pragma unroll
        for (int mt = 0; mt < 4; ++mt) {
            float4v d = __builtin_amdgcn_mfma_f32_16x16x32_bf16(
                            b0f[mt], xf[nt], zero4, 0, 0, 0);
            uint2 p;
            p.x = cvtpk(fmaxf(d[0], 0.f), fmaxf(d[1], 0.f));
            p.y = cvtpk(fmaxf(d[2], 0.f), fmaxf(d[3], 0.f));
            *(uint2*)&H[(r*64 + 16*mt + 4*lhi) ^ swz] = p;
        }
    }

    // ---- layer 1 (swapped): B-frags from H (reads precede overwrites) ----
    short8 h1f[2][2];
#pragma unroll
    for (int nt = 0; nt < 2; ++nt) {
        const int r = 16*nt + l15;
        const int swz = (r & 7) << 3;
#pragma unroll
        for (int ks = 0; ks < 2; ++ks)
            h1f[nt][ks] = *(const short8*)&H[(r*64 + 32*ks + 8*lhi) ^ swz];
    }
#pragma unroll
    for (int nt = 0; nt < 2; ++nt) {
        const int r = 16*nt + l15;
        const int swz = (r & 7) << 3;
#pragma unroll
        for (int mt = 0; mt < 4; ++mt) {
            float4v a = __builtin_amdgcn_mfma_f32_16x16x32_bf16(
                            b1f[0][mt], h1f[nt][0], b1vv[mt], 0, 0, 0);
            a = __builtin_amdgcn_mfma_f32_16x16x32_bf16(
                            b1f[1][mt], h1f[nt][1], a, 0, 0, 0);
            uint2 p;
            p.x = cvtpk(fmaxf(a[0], 0.f), fmaxf(a[1], 0.f));
            p.y = cvtpk(fmaxf(a[2], 0.f), fmaxf(a[3], 0.f));
            *(uint2*)&H[(r*64 + 16*mt + 4*lhi) ^ swz] = p;
        }
    }

    // ---- layer 2 (unswapped): A-frags from H, B-frags from W2L ----
    short8 a2[2][2];
#pragma unroll
    for (int m = 0; m < 2; ++m) {
        const int r = 16*m + l15;
        const int swz = (r & 7) << 3;
#pragma unroll
        for (int ks = 0; ks < 2; ++ks)
            a2[m][ks] = *(const short8*)&H[(r*64 + 32*ks + 8*lhi) ^ swz];
    }
    float* outp = feats + (size_t)g * 128;
    const int wswz = (l15 & 7) << 3;   // W2L read swizzle (o&7 == l15&7)

#pragma unroll 2
    for (int n = 0; n < 8; ++n) {
        short8 w2f0 = *(const short8*)&W2L[((16*n + l15)*64 +  0 + 8*lhi) ^ wswz];
        short8 w2f1 = *(const short8*)&W2L[((16*n + l15)*64 + 32 + 8*lhi) ^ wswz];
        float4v c0 = __builtin_amdgcn_mfma_f32_16x16x32_bf16(
                         a2[0][0], w2f0, zero4, 0, 0, 0);
        c0 = __builtin_amdgcn_mfma_f32_16x16x32_bf16(a2[0][1], w2f1, c0, 0, 0, 0);
        float4v c1 = __builtin_amdgcn_mfma_f32_16x16x32_bf16(
                         a2[1][0], w2f0, zero4, 0, 0, 0);
        c1 = __builtin_amdgcn_mfma_f32_16x16x32_bf16(a2[1][1], w2f1, c1, 0, 0, 0);
        float v = fmaxf(fmaxf(fmaxf(c0[0], c0[1]), fmaxf(c0[2], c0[3])),
                        fmaxf(fmaxf(c1[0], c1[1]), fmaxf(c1[2], c1[3])));
        v = fmaxf(v, __shfl_xor(v, 16, 64));
        v = fmaxf(v, __shfl_xor(v, 32, 64));
        if (l < 16)
            outp[16*n + l15] = fmaxf(v + b2v[n], 0.f);   // bias+relu after max
    }
}

extern "C" void kernel_launch(void* const* d_in, const int* in_sizes, int n_in,
                              void* d_out, int out_size, void* d_ws, size_t ws_size,
                              hipStream_t stream)
{
    const float* xg   = (const float*)d_in[0];
    const float* newx = (const float*)d_in[1];
    const float *W[3], *Bb[3], *G[3], *Be[3], *M[3], *V[3];
    for (int ll = 0; ll < 3; ++ll) {
        W[ll]  = (const float*)d_in[2 + 6*ll + 0];
        Bb[ll] = (const float*)d_in[2 + 6*ll + 1];
        G[ll]  = (const float*)d_in[2 + 6*ll + 2];
        Be[ll] = (const float*)d_in[2 + 6*ll + 3];
        M[ll]  = (const float*)d_in[2 + 6*ll + 4];
        V[ll]  = (const float*)d_in[2 + 6*ll + 5];
    }

    float* wsf = (float*)d_ws;

    fold_kernel<<<1, 256, 0, stream>>>(
        W[0], Bb[0], G[0], Be[0], M[0], V[0],
        W[1], Bb[1], G[1], Be[1], M[1], V[1],
        W[2], Bb[2], G[2], Be[2], M[2], V[2], wsf);

    copy_new_x<<<192, 256, 0, stream>>>((const float4*)newx, (float4*)d_out);

    float* feats = (float*)d_out + NEWX_ELEMS;
    sa_mfma_kernel<<<GRID, 512, 0, stream>>>(xg, wsf, feats);
}

// Round 14
// 127.255 us; speedup vs baseline: 1.6566x; 1.6566x over previous
//
#include <hip/hip_runtime.h>
#include <hip/hip_bf16.h>

#define EPS_BN 1e-5f

typedef __attribute__((ext_vector_type(8)))  short short8;    // 8 x bf16 (4 VGPR)
typedef __attribute__((ext_vector_type(4)))  float float4v;   // 16x16 acc
typedef __attribute__((ext_vector_type(16))) float float16v;  // 32x32 acc

constexpr int NEWX_ELEMS = 196608;    // B*P*3
constexpr int GRID       = 16384;     // 4 waves/block, 1 group/wave, GITER=1

// d_ws layout: f32 indices for folded f32 data, byte offsets for bf16 weights
constexpr int W0F = 0;      // f32[192]  W0' (64x3)
constexpr int B0F = 192;    // f32[64]
constexpr int B1F = 256;    // f32[64]
constexpr int B2F = 320;    // f32[128]
constexpr int W1B = 1792;   // bytes: ushort[4096]  W1' (64x64) bf16
constexpr int W2B = 10240;  // bytes: ushort[8192]  W2' (128x64) bf16

__device__ __forceinline__ unsigned short f2bf(float x) {
    return __builtin_bit_cast(unsigned short, __float2bfloat16(x));
}
__device__ __forceinline__ unsigned cvtpk(float a, float b) {
    unsigned r;
    asm("v_cvt_pk_bf16_f32 %0, %1, %2" : "=v"(r) : "v"(a), "v"(b));
    return r;
}

// Parallel fold: grid 32 x 256 (R13 postscript: the 1-block fold serialized
// ~3us ahead of the main kernel every call).
__global__ void fold_kernel(
    const float* w0, const float* b0, const float* g0,
    const float* be0, const float* m0, const float* v0,
    const float* w1, const float* b1, const float* g1,
    const float* be1, const float* m1, const float* v1,
    const float* w2, const float* b2, const float* g2,
    const float* be2, const float* m2, const float* v2,
    float* __restrict__ ws)
{
    const int tg = blockIdx.x * 256 + threadIdx.x;   // 0..8191
    ushort* w1b = (ushort*)((char*)ws + W1B);
    ushort* w2b = (ushort*)((char*)ws + W2B);
    if (tg < 64) {
        float s0 = g0[tg] * rsqrtf(v0[tg] + EPS_BN);
        ws[B0F + tg] = (b0[tg] - m0[tg]) * s0 + be0[tg];
        ws[W0F + tg*3 + 0] = w0[tg*3 + 0] * s0;
        ws[W0F + tg*3 + 1] = w0[tg*3 + 1] * s0;
        ws[W0F + tg*3 + 2] = w0[tg*3 + 2] * s0;
        float s1 = g1[tg] * rsqrtf(v1[tg] + EPS_BN);
        ws[B1F + tg] = (b1[tg] - m1[tg]) * s1 + be1[tg];
    }
    if (tg < 128) {
        float s2 = g2[tg] * rsqrtf(v2[tg] + EPS_BN);
        ws[B2F + tg] = (b2[tg] - m2[tg]) * s2 + be2[tg];
    }
    if (tg < 4096) {
        int o = tg >> 6;
        float s = g1[o] * rsqrtf(v1[o] + EPS_BN);
        w1b[tg] = f2bf(w1[tg] * s);
    }
    if (tg < 8192) {
        int o = tg >> 6;
        float s = g2[o] * rsqrtf(v2[o] + EPS_BN);
        w2b[tg] = f2bf(w2[tg] * s);
    }
}

// new_x passthrough, f32 -> f32
__global__ void copy_new_x(const float4* __restrict__ in, float4* __restrict__ out)
{
    int i = blockIdx.x * 256 + threadIdx.x;   // < 49,152
    out[i] = in[i];
}

// One wave = one group, straight-line. L0 = 16x16x32 (proven); L1/L2 =
// 32x32x16: one 32-sample tile spans the whole group, so (a) L1 is 8 MFMAs
// not 16, (b) L1-B and L2-A fragment reads share IDENTICAL addresses,
// (c) L2's D puts one out-channel per lane with 16 sample-values in-lane:
// epilogue = 15 in-lane fmax + ONE shfl + full-128B stores (R12's was
// 8 n-tiles x (7 fmax + 2 shfl + masked 64B store) ~ 2x the VALU).
// 32x32 layouts: D col=l&31, row=(reg&3)+8*(reg>>2)+4*(l>>5) [HW-verified];
// A/B: row/col=l&31, k = 8*(l>>5)+j (analogy w/ verified 16x16x32 mapping).
__global__ __launch_bounds__(256, 3) void sa_mfma_kernel(
    const float* __restrict__ xg,
    const float* __restrict__ wsf,
    float* __restrict__ feats)
{
    __shared__ __align__(16) ushort W2L[8192];      // 16KB swizzled W2'
    __shared__ __align__(16) ushort Hs[4][2048];    // 4 waves x 4KB (h1 then h2)

    const int tid = threadIdx.x;
    const int w   = tid >> 6;
    const int l   = tid & 63;
    const int l15 = l & 15;
    const int lhi = l >> 4;
    const int r31 = l & 31;
    const int hi5 = l >> 5;

    const ushort* w1b = (const ushort*)((const char*)wsf + W1B);
    const ushort* w2b = (const ushort*)((const char*)wsf + W2B);

    // ---- stage W2' into LDS (granule = 16B; gi = o*8 + c/8; dst = gi^(o&7))
    {
        const uint4* src = (const uint4*)w2b;   // 1024 granules
        uint4* dst = (uint4*)W2L;
        for (int gi = tid; gi < 1024; gi += 256)
            dst[gi ^ ((gi >> 3) & 7)] = src[gi];
    }

    ushort* H = Hs[w];
    const short8  zero8  = {0,0,0,0,0,0,0,0};
    const float4v zero4  = {0.f,0.f,0.f,0.f};

    const int g = blockIdx.x * 4 + w;   // one group per wave

    // ---- x load (lanes lhi==0: sample = 16nt + l15) ----
    float xr[2][3];
#pragma unroll
    for (int nt = 0; nt < 2; ++nt)
        if (lhi == 0) {
            const float* xp = xg + ((size_t)g*32 + 16*nt + l15) * 3;
            xr[nt][0] = xp[0]; xr[nt][1] = xp[1]; xr[nt][2] = xp[2];
        }

    // ---- L0 weight frag (16x16 layout) ----
    short8 b0f[4];
#pragma unroll
    for (int mt = 0; mt < 4; ++mt) {
        union { short8 v; unsigned d[4]; } f;
        f.v = zero8;
        if (lhi == 0) {
            int o = 16*mt + l15;
            f.d[0] = cvtpk(wsf[W0F + o*3 + 0], wsf[W0F + o*3 + 1]);
            f.d[1] = cvtpk(wsf[W0F + o*3 + 2], wsf[B0F + o]);
        }
        b0f[mt] = f.v;
    }

    // ---- L1 weight frags (32x32 layout): A row = ch r31+32ot, k = 16kt+8hi5+j
    short8 w1f[2][4];
#pragma unroll
    for (int ot = 0; ot < 2; ++ot)
#pragma unroll
        for (int kt = 0; kt < 4; ++kt)
            w1f[ot][kt] = *(const short8*)&w1b[(r31 + 32*ot)*64 + 16*kt + 8*hi5];

    // ---- L1 bias as 32x32 C-init: acc[4q+i] <- B1[i + 8q + 4hi5 + 32ot] ----
    float4v b1c[2][4];
#pragma unroll
    for (int ot = 0; ot < 2; ++ot)
#pragma unroll
        for (int q = 0; q < 4; ++q)
            b1c[ot][q] = *(const float4v*)&wsf[B1F + 32*ot + 8*q + 4*hi5];

    // ---- L2 bias: out-ch = r31 + 32bt ----
    float b2v[4];
#pragma unroll
    for (int bt = 0; bt < 4; ++bt)
        b2v[bt] = wsf[B2F + 32*bt + r31];

    __syncthreads();   // W2L ready

    // ---- x fragments ----
    short8 xf[2];
#pragma unroll
    for (int nt = 0; nt < 2; ++nt) {
        union { short8 v; unsigned d[4]; } f;
        f.v = zero8;
        if (lhi == 0) {
            f.d[0] = cvtpk(xr[nt][0], xr[nt][1]);
            f.d[1] = cvtpk(xr[nt][2], 1.0f);
        }
        xf[nt] = f.v;
    }

    // ---- layer 0 (16x16x32, swapped): rows 16nt+l15, ch 16mt+4lhi -> H ----
#pragma unroll
    for (int nt = 0; nt < 2; ++nt) {
        const int r = 16*nt + l15;
        const int swz = (r & 7) << 3;
#pragma unroll
        for (int mt = 0; mt < 4; ++mt) {
            float4v d = __builtin_amdgcn_mfma_f32_16x16x32_bf16(
                            b0f[mt], xf[nt], zero4, 0, 0, 0);
            uint2 p;
            p.x = cvtpk(fmaxf(d[0], 0.f), fmaxf(d[1], 0.f));
            p.y = cvtpk(fmaxf(d[2], 0.f), fmaxf(d[3], 0.f));
            *(uint2*)&H[(r*64 + 16*mt + 4*lhi) ^ swz] = p;
        }
    }

    // ---- shared fragment addresses: row r31, ch-chunk 16kt+8hi5 ----
    int haddr[4];
#pragma unroll
    for (int kt = 0; kt < 4; ++kt)
        haddr[kt] = (r31*64 + 16*kt + 8*hi5) ^ ((r31 & 7) << 3);

    // ---- layer 1 (32x32x16, swapped): B-frags from H, bias via C-init ----
    short8 hf[4];
#pragma unroll
    for (int kt = 0; kt < 4; ++kt)
        hf[kt] = *(const short8*)&H[haddr[kt]];

#pragma unroll
    for (int ot = 0; ot < 2; ++ot) {
        float16v acc;
#pragma unroll
        for (int q = 0; q < 4; ++q) {
            acc[4*q+0] = b1c[ot][q][0];
            acc[4*q+1] = b1c[ot][q][1];
            acc[4*q+2] = b1c[ot][q][2];
            acc[4*q+3] = b1c[ot][q][3];
        }
#pragma unroll
        for (int kt = 0; kt < 4; ++kt)
            acc = __builtin_amdgcn_mfma_f32_32x32x16_bf16(
                      w1f[ot][kt], hf[kt], acc, 0, 0, 0);
        // pack: lane holds ch = (reg&3)+8q+4hi5+32ot at sample r31
        const int swz = (r31 & 7) << 3;
#pragma unroll
        for (int q = 0; q < 4; ++q) {
            uint2 p;
            p.x = cvtpk(fmaxf(acc[4*q+0], 0.f), fmaxf(acc[4*q+1], 0.f));
            p.y = cvtpk(fmaxf(acc[4*q+2], 0.f), fmaxf(acc[4*q+3], 0.f));
            *(uint2*)&H[(r31*64 + 32*ot + 8*q + 4*hi5) ^ swz] = p;
        }
    }

    // ---- layer 2 (32x32x16, unswapped): A-frags at the SAME addresses ----
    short8 af[4];
#pragma unroll
    for (int kt = 0; kt < 4; ++kt)
        af[kt] = *(const short8*)&H[haddr[kt]];

    float* outp = feats + (size_t)g * 128;
#pragma unroll
    for (int bt = 0; bt < 4; ++bt) {
        const int o = r31 + 32*bt;            // out-channel (B col)
        float16v acc;
#pragma unroll
        for (int i = 0; i < 16; ++i) acc[i] = 0.f;
#pragma unroll
        for (int kt = 0; kt < 4; ++kt) {
            short8 wf = *(const short8*)&W2L[o*64 + (((2*kt + hi5) ^ (o & 7)) << 3)];
            acc = __builtin_amdgcn_mfma_f32_32x32x16_bf16(af[kt], wf, acc, 0, 0, 0);
        }
        // max over samples: 16 in-lane rows + partner lane (l^32) rows
        float m0 = fmaxf(fmaxf(acc[0],  acc[1]),  fmaxf(acc[2],  acc[3]));
        float m1 = fmaxf(fmaxf(acc[4],  acc[5]),  fmaxf(acc[6],  acc[7]));
        float m2 = fmaxf(fmaxf(acc[8],  acc[9]),  fmaxf(acc[10], acc[11]));
        float m3 = fmaxf(fmaxf(acc[12], acc[13]), fmaxf(acc[14], acc[15]));
        float m  = fmaxf(fmaxf(m0, m1), fmaxf(m2, m3));
        m = fmaxf(m, __shfl_xor(m, 32, 64));
        if (l < 32)
            outp[32*bt + r31] = fmaxf(m + b2v[bt], 0.f);   // bias+relu after max
    }
}

extern "C" void kernel_launch(void* const* d_in, const int* in_sizes, int n_in,
                              void* d_out, int out_size, void* d_ws, size_t ws_size,
                              hipStream_t stream)
{
    const float* xg   = (const float*)d_in[0];
    const float* newx = (const float*)d_in[1];
    const float *W[3], *Bb[3], *G[3], *Be[3], *M[3], *V[3];
    for (int ll = 0; ll < 3; ++ll) {
        W[ll]  = (const float*)d_in[2 + 6*ll + 0];
        Bb[ll] = (const float*)d_in[2 + 6*ll + 1];
        G[ll]  = (const float*)d_in[2 + 6*ll + 2];
        Be[ll] = (const float*)d_in[2 + 6*ll + 3];
        M[ll]  = (const float*)d_in[2 + 6*ll + 4];
        V[ll]  = (const float*)d_in[2 + 6*ll + 5];
    }

    float* wsf = (float*)d_ws;

    fold_kernel<<<32, 256, 0, stream>>>(
        W[0], Bb[0], G[0], Be[0], M[0], V[0],
        W[1], Bb[1], G[1], Be[1], M[1], V[1],
        W[2], Bb[2], G[2], Be[2], M[2], V[2], wsf);

    copy_new_x<<<192, 256, 0, stream>>>((const float4*)newx, (float4*)d_out);

    float* feats = (float*)d_out + NEWX_ELEMS;
    sa_mfma_kernel<<<GRID, 256, 0, stream>>>(xg, wsf, feats);
}

// Round 16
// 81.595 us; speedup vs baseline: 2.5836x; 1.5596x over previous
//
#include <hip/hip_runtime.h>
#include <hip/hip_bf16.h>

#define EPS_BN 1e-5f

typedef __attribute__((ext_vector_type(8)))  short short8;    // 8 x bf16
typedef __attribute__((ext_vector_type(4)))  float float4v;
typedef __attribute__((ext_vector_type(16))) float float16v;  // 32x32 acc

constexpr int NEWX_ELEMS = 196608;    // B*P*3
constexpr int GRID       = 4096;      // 4 waves/block, GITER groups/wave
constexpr int GITER      = 4;
constexpr int GSTRIDE    = GRID * 4;

constexpr int W0F = 0;      // f32[192]  W0' (64x3)
constexpr int B0F = 192;    // f32[64]
constexpr int B1F = 256;    // f32[64]
constexpr int B2F = 320;    // f32[128]
constexpr int W1B = 1792;   // bytes: ushort[4096]  W1' (64x64) bf16
constexpr int W2B = 10240;  // bytes: ushort[8192]  W2' (128x64) bf16

__device__ __forceinline__ unsigned short f2bf(float x) {
    return __builtin_bit_cast(unsigned short, __float2bfloat16(x));
}
__device__ __forceinline__ unsigned cvtpk(float a, float b) {
    unsigned r;
    asm("v_cvt_pk_bf16_f32 %0, %1, %2" : "=v"(r) : "v"(a), "v"(b));
    return r;
}
// gfx950 semantics (ISA + HK usage): vdst.high32 <-> vsrc.low32, i.e.
//   a' = { l<32: a_old[l],    l>=32: b_old[l-32] }   = {a.low, b.low}
//   b' = { l<32: a_old[l+32], l>=32: b_old[l]    }   = {a.high, b.high}
__device__ __forceinline__ void plswap(unsigned &a, unsigned &b) {
    asm("v_permlane32_swap_b32 %0, %1" : "+v"(a), "+v"(b));
}

__global__ void fold_kernel(
    const float* w0, const float* b0, const float* g0,
    const float* be0, const float* m0, const float* v0,
    const float* w1, const float* b1, const float* g1,
    const float* be1, const float* m1, const float* v1,
    const float* w2, const float* b2, const float* g2,
    const float* be2, const float* m2, const float* v2,
    float* __restrict__ ws)
{
    const int tg = blockIdx.x * 256 + threadIdx.x;   // 0..8191
    ushort* w1b = (ushort*)((char*)ws + W1B);
    ushort* w2b = (ushort*)((char*)ws + W2B);
    if (tg < 64) {
        float s0 = g0[tg] * rsqrtf(v0[tg] + EPS_BN);
        ws[B0F + tg] = (b0[tg] - m0[tg]) * s0 + be0[tg];
        ws[W0F + tg*3 + 0] = w0[tg*3 + 0] * s0;
        ws[W0F + tg*3 + 1] = w0[tg*3 + 1] * s0;
        ws[W0F + tg*3 + 2] = w0[tg*3 + 2] * s0;
        float s1 = g1[tg] * rsqrtf(v1[tg] + EPS_BN);
        ws[B1F + tg] = (b1[tg] - m1[tg]) * s1 + be1[tg];
    }
    if (tg < 128) {
        float s2 = g2[tg] * rsqrtf(v2[tg] + EPS_BN);
        ws[B2F + tg] = (b2[tg] - m2[tg]) * s2 + be2[tg];
    }
    if (tg < 4096) {
        int o = tg >> 6;
        float s = g1[o] * rsqrtf(v1[o] + EPS_BN);
        w1b[tg] = f2bf(w1[tg] * s);
    }
    if (tg < 8192) {
        int o = tg >> 6;
        float s = g2[o] * rsqrtf(v2[o] + EPS_BN);
        w2b[tg] = f2bf(w2[tg] * s);
    }
}

__global__ void copy_new_x(const float4* __restrict__ in, float4* __restrict__ out)
{
    int i = blockIdx.x * 256 + threadIdx.x;   // < 49,152
    out[i] = in[i];
}

// All-register layer chain, 32x32x16 MFMA throughout. Layer-output acc
// layout (ch=(reg&3)+8q+4hi5 @ sample col l&31) redistributes to the next
// layer's fragment layout (k=8hi5+j) with v_permlane32_swap_b32 under the
// CORRECT gfx950 semantics (vdst.high <-> vsrc.low):
//   plswap(p[4kt], p[4kt+2])   -> d[0] = {own-q lo}, d[2] = {hi halves}
//   plswap(p[4kt+1], p[4kt+3]) -> d[1], d[3]
// (R15 had the halves crossed -> absmax 6.33.) No LDS H tiles; W2 in LDS
// restaged [chunk][o] so each 32-lane half reads 512 contiguous bytes.
__global__ __launch_bounds__(256, 3) void sa_mfma_kernel(
    const float* __restrict__ xg,
    const float* __restrict__ wsf,
    float* __restrict__ feats)
{
    __shared__ __align__(16) ushort W2L[8192];   // 16KB: granule[c][o], c=0..7

    const int tid = threadIdx.x;
    const int w   = tid >> 6;
    const int l   = tid & 63;
    const int r31 = l & 31;
    const int hi5 = l >> 5;

    const ushort* w1b = (const ushort*)((const char*)wsf + W1B);
    const ushort* w2b = (const ushort*)((const char*)wsf + W2B);

    // stage W2': src granule gi=(o*8+c) -> dst (c<<7)|o
    {
        const uint4* src = (const uint4*)w2b;
        uint4* dst = (uint4*)W2L;
        for (int gi = tid; gi < 1024; gi += 256)
            dst[((gi & 7) << 7) | (gi >> 3)] = src[gi];
    }

    const short8 zero8 = {0,0,0,0,0,0,0,0};
    float16v zero16;
#pragma unroll
    for (int i = 0; i < 16; ++i) zero16[i] = 0.f;

    // ---- weights (hoisted, GITER-amortized) ----
    short8 w0f[2];
#pragma unroll
    for (int ot = 0; ot < 2; ++ot) {
        union { short8 v; unsigned d[4]; } f;
        f.v = zero8;
        if (hi5 == 0) {
            int o = r31 + 32*ot;
            f.d[0] = cvtpk(wsf[W0F + o*3 + 0], wsf[W0F + o*3 + 1]);
            f.d[1] = cvtpk(wsf[W0F + o*3 + 2], wsf[B0F + o]);
        }
        w0f[ot] = f.v;
    }
    short8 w1f[2][4];
#pragma unroll
    for (int ot = 0; ot < 2; ++ot)
#pragma unroll
        for (int kt = 0; kt < 4; ++kt)
            w1f[ot][kt] = *(const short8*)&w1b[(r31 + 32*ot)*64 + 16*kt + 8*hi5];
    float4v b1c[2][4];
#pragma unroll
    for (int ot = 0; ot < 2; ++ot)
#pragma unroll
        for (int q = 0; q < 4; ++q)
            b1c[ot][q] = *(const float4v*)&wsf[B1F + 32*ot + 8*q + 4*hi5];
    float b2v[4];
#pragma unroll
    for (int bt = 0; bt < 4; ++bt)
        b2v[bt] = wsf[B2F + 32*bt + r31];

    __syncthreads();   // W2L ready

    const int wid = blockIdx.x * 4 + w;

    float xr[3];
    if (hi5 == 0) {
        const float* xp = xg + ((size_t)wid*32 + r31) * 3;
        xr[0] = xp[0]; xr[1] = xp[1]; xr[2] = xp[2];
    }

#pragma unroll 1
    for (int it = 0; it < GITER; ++it) {
        const int g = wid + it * GSTRIDE;

        // x fragment (col = sample r31, k<4 = {x0,x1,x2,1}, hi5==0 half)
        short8 xf;
        {
            union { short8 v; unsigned d[4]; } f;
            f.v = zero8;
            if (hi5 == 0) {
                f.d[0] = cvtpk(xr[0], xr[1]);
                f.d[1] = cvtpk(xr[2], 1.0f);
            }
            xf = f.v;
        }
        if (it + 1 < GITER && hi5 == 0) {
            const float* xp = xg + ((size_t)(g + GSTRIDE)*32 + r31) * 3;
            xr[0] = xp[0]; xr[1] = xp[1]; xr[2] = xp[2];
        }

        // ---- L0: 2 MFMA; relu+pack+swap -> h1f[4] ----
        short8 h1f[4];
#pragma unroll
        for (int ot = 0; ot < 2; ++ot) {
            float16v a = __builtin_amdgcn_mfma_f32_32x32x16_bf16(
                             w0f[ot], xf, zero16, 0, 0, 0);
            unsigned p[8];
#pragma unroll
            for (int q = 0; q < 4; ++q) {
                p[2*q]   = cvtpk(fmaxf(a[4*q+0], 0.f), fmaxf(a[4*q+1], 0.f));
                p[2*q+1] = cvtpk(fmaxf(a[4*q+2], 0.f), fmaxf(a[4*q+3], 0.f));
            }
            union { short8 v; unsigned d[4]; } f0, f1;
            unsigned A = p[0], B = p[2];  plswap(A, B);
            f0.d[0] = A; f0.d[2] = B;
            unsigned C = p[1], D = p[3];  plswap(C, D);
            f0.d[1] = C; f0.d[3] = D;
            unsigned E = p[4], F = p[6];  plswap(E, F);
            f1.d[0] = E; f1.d[2] = F;
            unsigned G = p[5], Hh = p[7]; plswap(G, Hh);
            f1.d[1] = G; f1.d[3] = Hh;
            h1f[2*ot]   = f0.v;
            h1f[2*ot+1] = f1.v;
        }

        // ---- L1: 8 MFMA (bias C-init); relu+pack+swap -> h2f[4] ----
        short8 h2f[4];
#pragma unroll
        for (int ot = 0; ot < 2; ++ot) {
            float16v a;
#pragma unroll
            for (int q = 0; q < 4; ++q) {
                a[4*q+0] = b1c[ot][q][0];
                a[4*q+1] = b1c[ot][q][1];
                a[4*q+2] = b1c[ot][q][2];
                a[4*q+3] = b1c[ot][q][3];
            }
#pragma unroll
            for (int kt = 0; kt < 4; ++kt)
                a = __builtin_amdgcn_mfma_f32_32x32x16_bf16(
                        w1f[ot][kt], h1f[kt], a, 0, 0, 0);
            unsigned p[8];
#pragma unroll
            for (int q = 0; q < 4; ++q) {
                p[2*q]   = cvtpk(fmaxf(a[4*q+0], 0.f), fmaxf(a[4*q+1], 0.f));
                p[2*q+1] = cvtpk(fmaxf(a[4*q+2], 0.f), fmaxf(a[4*q+3], 0.f));
            }
            union { short8 v; unsigned d[4]; } f0, f1;
            unsigned A = p[0], B = p[2];  plswap(A, B);
            f0.d[0] = A; f0.d[2] = B;
            unsigned C = p[1], D = p[3];  plswap(C, D);
            f0.d[1] = C; f0.d[3] = D;
            unsigned E = p[4], F = p[6];  plswap(E, F);
            f1.d[0] = E; f1.d[2] = F;
            unsigned G = p[5], Hh = p[7]; plswap(G, Hh);
            f1.d[1] = G; f1.d[3] = Hh;
            h2f[2*ot]   = f0.v;
            h2f[2*ot+1] = f1.v;
        }

        // ---- L2: 16 MFMA, W2 frags from W2L ([c][o] layout, conflict-free)
        float* outp = feats + (size_t)g * 128;
#pragma unroll 2
        for (int bt = 0; bt < 4; ++bt) {
            float16v a = zero16;
#pragma unroll
            for (int kt = 0; kt < 4; ++kt) {
                short8 wf = *(const short8*)
                    &W2L[(((2*kt + hi5) << 7) + 32*bt + r31) * 8];
                a = __builtin_amdgcn_mfma_f32_32x32x16_bf16(
                        h2f[kt], wf, a, 0, 0, 0);
            }
            float m0 = fmaxf(fmaxf(a[0],  a[1]),  fmaxf(a[2],  a[3]));
            float m1 = fmaxf(fmaxf(a[4],  a[5]),  fmaxf(a[6],  a[7]));
            float m2 = fmaxf(fmaxf(a[8],  a[9]),  fmaxf(a[10], a[11]));
            float m3 = fmaxf(fmaxf(a[12], a[13]), fmaxf(a[14], a[15]));
            float m  = fmaxf(fmaxf(m0, m1), fmaxf(m2, m3));
            m = fmaxf(m, __shfl_xor(m, 32, 64));
            if (l < 32)
                outp[32*bt + r31] = fmaxf(m + b2v[bt], 0.f);
        }
    }
}

extern "C" void kernel_launch(void* const* d_in, const int* in_sizes, int n_in,
                              void* d_out, int out_size, void* d_ws, size_t ws_size,
                              hipStream_t stream)
{
    const float* xg   = (const float*)d_in[0];
    const float* newx = (const float*)d_in[1];
    const float *W[3], *Bb[3], *G[3], *Be[3], *M[3], *V[3];
    for (int ll = 0; ll < 3; ++ll) {
        W[ll]  = (const float*)d_in[2 + 6*ll + 0];
        Bb[ll] = (const float*)d_in[2 + 6*ll + 1];
        G[ll]  = (const float*)d_in[2 + 6*ll + 2];
        Be[ll] = (const float*)d_in[2 + 6*ll + 3];
        M[ll]  = (const float*)d_in[2 + 6*ll + 4];
        V[ll]  = (const float*)d_in[2 + 6*ll + 5];
    }

    float* wsf = (float*)d_ws;

    fold_kernel<<<32, 256, 0, stream>>>(
        W[0], Bb[0], G[0], Be[0], M[0], V[0],
        W[1], Bb[1], G[1], Be[1], M[1], V[1],
        W[2], Bb[2], G[2], Be[2], M[2], V[2], wsf);

    copy_new_x<<<192, 256, 0, stream>>>((const float4*)newx, (float4*)d_out);

    float* feats = (float*)d_out + NEWX_ELEMS;
    sa_mfma_kernel<<<GRID, 256, 0, stream>>>(xg, wsf, feats);
}

// Round 17
// 80.648 us; speedup vs baseline: 2.6140x; 1.0117x over previous
//
#include <hip/hip_runtime.h>
#include <hip/hip_bf16.h>

#define EPS_BN 1e-5f

typedef __attribute__((ext_vector_type(8)))  short short8;    // 8 x bf16
typedef __attribute__((ext_vector_type(4)))  float float4v;
typedef __attribute__((ext_vector_type(16))) float float16v;  // 32x32 acc

constexpr int NEWX_ELEMS = 196608;    // B*P*3
constexpr int GRID       = 2048;      // 4 waves/block
constexpr int NITER      = 4;         // iters/wave, 2 groups per iter
constexpr int NWAVES     = GRID * 4;  // 8192
constexpr int HALF       = 32768;     // groups handled as "B" start here

constexpr int W0F = 0;      // f32[192]  W0' (64x3)
constexpr int B0F = 192;    // f32[64]
constexpr int B1F = 256;    // f32[64]
constexpr int B2F = 320;    // f32[128]
constexpr int W1B = 1792;   // bytes: ushort[4096]  W1' (64x64) bf16
constexpr int W2B = 10240;  // bytes: ushort[8192]  W2' (128x64) bf16

__device__ __forceinline__ unsigned short f2bf(float x) {
    return __builtin_bit_cast(unsigned short, __float2bfloat16(x));
}
__device__ __forceinline__ unsigned cvtpk(float a, float b) {
    unsigned r;
    asm("v_cvt_pk_bf16_f32 %0, %1, %2" : "=v"(r) : "v"(a), "v"(b));
    return r;
}
// gfx950: vdst.high32 <-> vsrc.low32  (HW-validated R16)
__device__ __forceinline__ void plswap(unsigned &a, unsigned &b) {
    asm("v_permlane32_swap_b32 %0, %1" : "+v"(a), "+v"(b));
}

__global__ void fold_kernel(
    const float* w0, const float* b0, const float* g0,
    const float* be0, const float* m0, const float* v0,
    const float* w1, const float* b1, const float* g1,
    const float* be1, const float* m1, const float* v1,
    const float* w2, const float* b2, const float* g2,
    const float* be2, const float* m2, const float* v2,
    float* __restrict__ ws)
{
    const int tg = blockIdx.x * 256 + threadIdx.x;   // 0..8191
    ushort* w1b = (ushort*)((char*)ws + W1B);
    ushort* w2b = (ushort*)((char*)ws + W2B);
    if (tg < 64) {
        float s0 = g0[tg] * rsqrtf(v0[tg] + EPS_BN);
        ws[B0F + tg] = (b0[tg] - m0[tg]) * s0 + be0[tg];
        ws[W0F + tg*3 + 0] = w0[tg*3 + 0] * s0;
        ws[W0F + tg*3 + 1] = w0[tg*3 + 1] * s0;
        ws[W0F + tg*3 + 2] = w0[tg*3 + 2] * s0;
        float s1 = g1[tg] * rsqrtf(v1[tg] + EPS_BN);
        ws[B1F + tg] = (b1[tg] - m1[tg]) * s1 + be1[tg];
    }
    if (tg < 128) {
        float s2 = g2[tg] * rsqrtf(v2[tg] + EPS_BN);
        ws[B2F + tg] = (b2[tg] - m2[tg]) * s2 + be2[tg];
    }
    if (tg < 4096) {
        int o = tg >> 6;
        float s = g1[o] * rsqrtf(v1[o] + EPS_BN);
        w1b[tg] = f2bf(w1[tg] * s);
    }
    if (tg < 8192) {
        int o = tg >> 6;
        float s = g2[o] * rsqrtf(v2[o] + EPS_BN);
        w2b[tg] = f2bf(w2[tg] * s);
    }
}

__global__ void copy_new_x(const float4* __restrict__ in, float4* __restrict__ out)
{
    int i = blockIdx.x * 256 + threadIdx.x;   // < 49,152
    out[i] = in[i];
}

// Dual-group all-register chain (R16 structure x2): two independent layer
// chains per wave, interleaved -- chain B fills chain A's MFMA/pack latency
// (the R16 counters showed ~2.2 waves/SIMD can't cover the serial chain).
// Weights fully shared; W2L ds_reads amortize over 2 groups. b1c passed
// directly as MFMA C-operand (no acc-init copies). lb(256,2): peak live
// ~160 regs incl acc -- no spill (cap 256).
__global__ __launch_bounds__(256, 2) void sa_mfma_kernel(
    const float* __restrict__ xg,
    const float* __restrict__ wsf,
    float* __restrict__ feats)
{
    __shared__ __align__(16) ushort W2L[8192];   // 16KB: granule[c][o], c=0..7

    const int tid = threadIdx.x;
    const int w   = tid >> 6;
    const int l   = tid & 63;
    const int r31 = l & 31;
    const int hi5 = l >> 5;

    const ushort* w1b = (const ushort*)((const char*)wsf + W1B);
    const ushort* w2b = (const ushort*)((const char*)wsf + W2B);

    // stage W2': src granule gi=(o*8+c) -> dst (c<<7)|o
    {
        const uint4* src = (const uint4*)w2b;
        uint4* dst = (uint4*)W2L;
        for (int gi = tid; gi < 1024; gi += 256)
            dst[((gi & 7) << 7) | (gi >> 3)] = src[gi];
    }

    const short8 zero8 = {0,0,0,0,0,0,0,0};
    float16v zero16;
#pragma unroll
    for (int i = 0; i < 16; ++i) zero16[i] = 0.f;

    // ---- weights (hoisted) ----
    short8 w0f[2];
#pragma unroll
    for (int ot = 0; ot < 2; ++ot) {
        union { short8 v; unsigned d[4]; } f;
        f.v = zero8;
        if (hi5 == 0) {
            int o = r31 + 32*ot;
            f.d[0] = cvtpk(wsf[W0F + o*3 + 0], wsf[W0F + o*3 + 1]);
            f.d[1] = cvtpk(wsf[W0F + o*3 + 2], wsf[B0F + o]);
        }
        w0f[ot] = f.v;
    }
    short8 w1f[2][4];
#pragma unroll
    for (int ot = 0; ot < 2; ++ot)
#pragma unroll
        for (int kt = 0; kt < 4; ++kt)
            w1f[ot][kt] = *(const short8*)&w1b[(r31 + 32*ot)*64 + 16*kt + 8*hi5];
    float16v b1cv[2];   // bias as direct MFMA C-operand
#pragma unroll
    for (int ot = 0; ot < 2; ++ot)
#pragma unroll
        for (int q = 0; q < 4; ++q) {
            float4v t = *(const float4v*)&wsf[B1F + 32*ot + 8*q + 4*hi5];
            b1cv[ot][4*q+0] = t[0]; b1cv[ot][4*q+1] = t[1];
            b1cv[ot][4*q+2] = t[2]; b1cv[ot][4*q+3] = t[3];
        }
    float b2v[4];
#pragma unroll
    for (int bt = 0; bt < 4; ++bt)
        b2v[bt] = wsf[B2F + 32*bt + r31];

    __syncthreads();   // W2L ready

    const int wid = blockIdx.x * 4 + w;

    // pack+swap: acc layout -> next-layer fragment pair (validated R16)
    auto packswap = [&](const float16v &a, short8 &lo, short8 &hi) {
        unsigned p[8];
#pragma unroll
        for (int q = 0; q < 4; ++q) {
            p[2*q]   = cvtpk(fmaxf(a[4*q+0], 0.f), fmaxf(a[4*q+1], 0.f));
            p[2*q+1] = cvtpk(fmaxf(a[4*q+2], 0.f), fmaxf(a[4*q+3], 0.f));
        }
        union { short8 v; unsigned d[4]; } f0, f1;
        unsigned A = p[0], B = p[2];  plswap(A, B);
        f0.d[0] = A; f0.d[2] = B;
        unsigned C = p[1], D = p[3];  plswap(C, D);
        f0.d[1] = C; f0.d[3] = D;
        unsigned E = p[4], F = p[6];  plswap(E, F);
        f1.d[0] = E; f1.d[2] = F;
        unsigned G = p[5], Hh = p[7]; plswap(G, Hh);
        f1.d[1] = G; f1.d[3] = Hh;
        lo = f0.v; hi = f1.v;
    };

    float xrA[3], xrB[3];
    if (hi5 == 0) {
        const float* xa = xg + ((size_t)wid*32 + r31) * 3;
        xrA[0] = xa[0]; xrA[1] = xa[1]; xrA[2] = xa[2];
        const float* xb = xg + ((size_t)(wid + HALF)*32 + r31) * 3;
        xrB[0] = xb[0]; xrB[1] = xb[1]; xrB[2] = xb[2];
    }

#pragma unroll 1
    for (int it = 0; it < NITER; ++it) {
        const int gA = wid + it * NWAVES;
        const int gB = gA + HALF;

        // x fragments (col = sample r31, k<4 = {x0,x1,x2,1}, hi5==0 half)
        short8 xfA, xfB;
        {
            union { short8 v; unsigned d[4]; } fa, fb;
            fa.v = zero8; fb.v = zero8;
            if (hi5 == 0) {
                fa.d[0] = cvtpk(xrA[0], xrA[1]);
                fa.d[1] = cvtpk(xrA[2], 1.0f);
                fb.d[0] = cvtpk(xrB[0], xrB[1]);
                fb.d[1] = cvtpk(xrB[2], 1.0f);
            }
            xfA = fa.v; xfB = fb.v;
        }
        if (it + 1 < NITER && hi5 == 0) {
            const float* xa = xg + ((size_t)(gA + NWAVES)*32 + r31) * 3;
            xrA[0] = xa[0]; xrA[1] = xa[1]; xrA[2] = xa[2];
            const float* xb = xg + ((size_t)(gB + NWAVES)*32 + r31) * 3;
            xrB[0] = xb[0]; xrB[1] = xb[1]; xrB[2] = xb[2];
        }

        // ---- L0: 4 MFMA (2 ot x {A,B}); pack+swap -> h1fA/h1fB ----
        short8 h1fA[4], h1fB[4];
#pragma unroll
        for (int ot = 0; ot < 2; ++ot) {
            float16v aA = __builtin_amdgcn_mfma_f32_32x32x16_bf16(
                              w0f[ot], xfA, zero16, 0, 0, 0);
            float16v aB = __builtin_amdgcn_mfma_f32_32x32x16_bf16(
                              w0f[ot], xfB, zero16, 0, 0, 0);
            packswap(aA, h1fA[2*ot], h1fA[2*ot+1]);
            packswap(aB, h1fB[2*ot], h1fB[2*ot+1]);
        }

        // ---- L1: 8 MFMA (bias via C-operand); pack+swap -> h2fA/h2fB ----
        short8 h2fA[4], h2fB[4];
#pragma unroll
        for (int ot = 0; ot < 2; ++ot) {
            float16v aA = b1cv[ot];
            float16v aB = b1cv[ot];
#pragma unroll
            for (int kt = 0; kt < 4; ++kt) {
                aA = __builtin_amdgcn_mfma_f32_32x32x16_bf16(
                         w1f[ot][kt], h1fA[kt], aA, 0, 0, 0);
                aB = __builtin_amdgcn_mfma_f32_32x32x16_bf16(
                         w1f[ot][kt], h1fB[kt], aB, 0, 0, 0);
            }
            packswap(aA, h2fA[2*ot], h2fA[2*ot+1]);
            packswap(aB, h2fB[2*ot], h2fB[2*ot+1]);
        }

        // ---- L2: 32 MFMA for 2 groups; shared W2 frags from W2L ----
        float* outpA = feats + (size_t)gA * 128;
        float* outpB = feats + (size_t)gB * 128;
#pragma unroll 2
        for (int bt = 0; bt < 4; ++bt) {
            float16v aA = zero16;
            float16v aB = zero16;
#pragma unroll
            for (int kt = 0; kt < 4; ++kt) {
                short8 wf = *(const short8*)
                    &W2L[(((2*kt + hi5) << 7) + 32*bt + r31) * 8];
                aA = __builtin_amdgcn_mfma_f32_32x32x16_bf16(
                         h2fA[kt], wf, aA, 0, 0, 0);
                aB = __builtin_amdgcn_mfma_f32_32x32x16_bf16(
                         h2fB[kt], wf, aB, 0, 0, 0);
            }
            float mA = fmaxf(
                fmaxf(fmaxf(fmaxf(aA[0], aA[1]),  fmaxf(aA[2],  aA[3])),
                      fmaxf(fmaxf(aA[4], aA[5]),  fmaxf(aA[6],  aA[7]))),
                fmaxf(fmaxf(fmaxf(aA[8], aA[9]),  fmaxf(aA[10], aA[11])),
                      fmaxf(fmaxf(aA[12],aA[13]), fmaxf(aA[14], aA[15]))));
            float mB = fmaxf(
                fmaxf(fmaxf(fmaxf(aB[0], aB[1]),  fmaxf(aB[2],  aB[3])),
                      fmaxf(fmaxf(aB[4], aB[5]),  fmaxf(aB[6],  aB[7]))),
                fmaxf(fmaxf(fmaxf(aB[8], aB[9]),  fmaxf(aB[10], aB[11])),
                      fmaxf(fmaxf(aB[12],aB[13]), fmaxf(aB[14], aB[15]))));
            mA = fmaxf(mA, __shfl_xor(mA, 32, 64));
            mB = fmaxf(mB, __shfl_xor(mB, 32, 64));
            if (l < 32) {
                outpA[32*bt + r31] = fmaxf(mA + b2v[bt], 0.f);
                outpB[32*bt + r31] = fmaxf(mB + b2v[bt], 0.f);
            }
        }
    }
}

extern "C" void kernel_launch(void* const* d_in, const int* in_sizes, int n_in,
                              void* d_out, int out_size, void* d_ws, size_t ws_size,
                              hipStream_t stream)
{
    const float* xg   = (const float*)d_in[0];
    const float* newx = (const float*)d_in[1];
    const float *W[3], *Bb[3], *G[3], *Be[3], *M[3], *V[3];
    for (int ll = 0; ll < 3; ++ll) {
        W[ll]  = (const float*)d_in[2 + 6*ll + 0];
        Bb[ll] = (const float*)d_in[2 + 6*ll + 1];
        G[ll]  = (const float*)d_in[2 + 6*ll + 2];
        Be[ll] = (const float*)d_in[2 + 6*ll + 3];
        M[ll]  = (const float*)d_in[2 + 6*ll + 4];
        V[ll]  = (const float*)d_in[2 + 6*ll + 5];
    }

    float* wsf = (float*)d_ws;

    fold_kernel<<<32, 256, 0, stream>>>(
        W[0], Bb[0], G[0], Be[0], M[0], V[0],
        W[1], Bb[1], G[1], Be[1], M[1], V[1],
        W[2], Bb[2], G[2], Be[2], M[2], V[2], wsf);

    copy_new_x<<<192, 256, 0, stream>>>((const float4*)newx, (float4*)d_out);

    float* feats = (float*)d_out + NEWX_ELEMS;
    sa_mfma_kernel<<<GRID, 256, 0, stream>>>(xg, wsf, feats);
}

// Round 18
// 80.640 us; speedup vs baseline: 2.6142x; 1.0001x over previous
//
#include <hip/hip_runtime.h>
#include <hip/hip_bf16.h>

#define EPS_BN 1e-5f

typedef __attribute__((ext_vector_type(8)))  short short8;    // 8 x bf16
typedef __attribute__((ext_vector_type(4)))  float float4v;
typedef __attribute__((ext_vector_type(16))) float float16v;  // 32x32 acc

constexpr int NEWX_ELEMS = 196608;    // B*P*3
constexpr int GRID       = 4096;      // 4 waves/block, GITER groups/wave
constexpr int GITER      = 4;
constexpr int GSTRIDE    = GRID * 4;

constexpr int W0F = 0;      // f32[192]  W0' (64x3)
constexpr int B0F = 192;    // f32[64]
constexpr int B1F = 256;    // f32[64]
constexpr int B2F = 320;    // f32[128]
constexpr int W1B = 1792;   // bytes: ushort[4096]  W1' (64x64) bf16
constexpr int W2B = 10240;  // bytes: ushort[8192]  W2' (128x64) bf16

__device__ __forceinline__ unsigned short f2bf(float x) {
    return __builtin_bit_cast(unsigned short, __float2bfloat16(x));
}
__device__ __forceinline__ unsigned cvtpk(float a, float b) {
    unsigned r;
    asm("v_cvt_pk_bf16_f32 %0, %1, %2" : "=v"(r) : "v"(a), "v"(b));
    return r;
}
// gfx950: vdst.high32 <-> vsrc.low32  (HW-validated R16)
__device__ __forceinline__ void plswap(unsigned &a, unsigned &b) {
    asm("v_permlane32_swap_b32 %0, %1" : "+v"(a), "+v"(b));
}

__global__ void fold_kernel(
    const float* w0, const float* b0, const float* g0,
    const float* be0, const float* m0, const float* v0,
    const float* w1, const float* b1, const float* g1,
    const float* be1, const float* m1, const float* v1,
    const float* w2, const float* b2, const float* g2,
    const float* be2, const float* m2, const float* v2,
    float* __restrict__ ws)
{
    const int tg = blockIdx.x * 256 + threadIdx.x;   // 0..8191
    ushort* w1b = (ushort*)((char*)ws + W1B);
    ushort* w2b = (ushort*)((char*)ws + W2B);
    if (tg < 64) {
        float s0 = g0[tg] * rsqrtf(v0[tg] + EPS_BN);
        ws[B0F + tg] = (b0[tg] - m0[tg]) * s0 + be0[tg];
        ws[W0F + tg*3 + 0] = w0[tg*3 + 0] * s0;
        ws[W0F + tg*3 + 1] = w0[tg*3 + 1] * s0;
        ws[W0F + tg*3 + 2] = w0[tg*3 + 2] * s0;
        float s1 = g1[tg] * rsqrtf(v1[tg] + EPS_BN);
        ws[B1F + tg] = (b1[tg] - m1[tg]) * s1 + be1[tg];
    }
    if (tg < 128) {
        float s2 = g2[tg] * rsqrtf(v2[tg] + EPS_BN);
        ws[B2F + tg] = (b2[tg] - m2[tg]) * s2 + be2[tg];
    }
    if (tg < 4096) {
        int o = tg >> 6;
        float s = g1[o] * rsqrtf(v1[o] + EPS_BN);
        w1b[tg] = f2bf(w1[tg] * s);
    }
    if (tg < 8192) {
        int o = tg >> 6;
        float s = g2[o] * rsqrtf(v2[o] + EPS_BN);
        w2b[tg] = f2bf(w2[tg] * s);
    }
}

__global__ void copy_new_x(const float4* __restrict__ in, float4* __restrict__ out)
{
    int i = blockIdx.x * 256 + threadIdx.x;   // < 49,152
    out[i] = in[i];
}

// Single-chain all-register pipeline (R16), with W1 and B1 ALSO evicted to
// LDS: frees ~64 VGPRs of hoisted weights so the allocator can fit 4-6
// waves/SIMD (R16/R17 both plateaued at ~3 independent chains/SIMD; chain
// count is the measured limiter). No launch_bounds min-waves: every forced
// bound (R5/R9/R13) backfired; R16 proved the pressure heuristic keeps
// loop-invariant LDS reads in-loop. W1L/W2L both in conflict-free
// [chunk][row] granule layout; B1L reads are wave-broadcast (2 addrs).
__global__ __launch_bounds__(256) void sa_mfma_kernel(
    const float* __restrict__ xg,
    const float* __restrict__ wsf,
    float* __restrict__ feats)
{
    __shared__ __align__(16) ushort W2L[8192];   // 16KB: granule[c 0..7][o 0..127]
    __shared__ __align__(16) ushort W1L[4096];   // 8KB:  granule[c 0..7][o 0..63]
    __shared__ __align__(16) float  B1L[64];     // 256B

    const int tid = threadIdx.x;
    const int w   = tid >> 6;
    const int l   = tid & 63;
    const int r31 = l & 31;
    const int hi5 = l >> 5;

    const ushort* w1b = (const ushort*)((const char*)wsf + W1B);
    const ushort* w2b = (const ushort*)((const char*)wsf + W2B);

    // stage W2' (1024 granules): src gi=(o*8+c) -> dst (c<<7)|o
    {
        const uint4* src = (const uint4*)w2b;
        uint4* dst = (uint4*)W2L;
        for (int gi = tid; gi < 1024; gi += 256)
            dst[((gi & 7) << 7) | (gi >> 3)] = src[gi];
    }
    // stage W1' (512 granules): src gi=(o*8+c) -> dst (c<<6)|o
    {
        const uint4* src = (const uint4*)w1b;
        uint4* dst = (uint4*)W1L;
        for (int gi = tid; gi < 512; gi += 256)
            dst[((gi & 7) << 6) | (gi >> 3)] = src[gi];
    }
    if (tid < 64) B1L[tid] = wsf[B1F + tid];

    const short8 zero8 = {0,0,0,0,0,0,0,0};
    float16v zero16;
#pragma unroll
    for (int i = 0; i < 16; ++i) zero16[i] = 0.f;

    // ---- remaining hoisted weights (small): w0f 8 regs, b2v 4 regs ----
    short8 w0f[2];
#pragma unroll
    for (int ot = 0; ot < 2; ++ot) {
        union { short8 v; unsigned d[4]; } f;
        f.v = zero8;
        if (hi5 == 0) {
            int o = r31 + 32*ot;
            f.d[0] = cvtpk(wsf[W0F + o*3 + 0], wsf[W0F + o*3 + 1]);
            f.d[1] = cvtpk(wsf[W0F + o*3 + 2], wsf[B0F + o]);
        }
        w0f[ot] = f.v;
    }
    float b2v[4];
#pragma unroll
    for (int bt = 0; bt < 4; ++bt)
        b2v[bt] = wsf[B2F + 32*bt + r31];

    __syncthreads();   // W2L/W1L/B1L ready

    const int wid = blockIdx.x * 4 + w;

    // pack+swap: acc layout -> next-layer fragment pair (validated R16)
    auto packswap = [&](const float16v &a, short8 &lo, short8 &hi) {
        unsigned p[8];
#pragma unroll
        for (int q = 0; q < 4; ++q) {
            p[2*q]   = cvtpk(fmaxf(a[4*q+0], 0.f), fmaxf(a[4*q+1], 0.f));
            p[2*q+1] = cvtpk(fmaxf(a[4*q+2], 0.f), fmaxf(a[4*q+3], 0.f));
        }
        union { short8 v; unsigned d[4]; } f0, f1;
        unsigned A = p[0], B = p[2];  plswap(A, B);
        f0.d[0] = A; f0.d[2] = B;
        unsigned C = p[1], D = p[3];  plswap(C, D);
        f0.d[1] = C; f0.d[3] = D;
        unsigned E = p[4], F = p[6];  plswap(E, F);
        f1.d[0] = E; f1.d[2] = F;
        unsigned G = p[5], Hh = p[7]; plswap(G, Hh);
        f1.d[1] = G; f1.d[3] = Hh;
        lo = f0.v; hi = f1.v;
    };

    float xr[3];
    if (hi5 == 0) {
        const float* xp = xg + ((size_t)wid*32 + r31) * 3;
        xr[0] = xp[0]; xr[1] = xp[1]; xr[2] = xp[2];
    }

#pragma unroll 1
    for (int it = 0; it < GITER; ++it) {
        const int g = wid + it * GSTRIDE;

        // x fragment (col = sample r31, k<4 = {x0,x1,x2,1}, hi5==0 half)
        short8 xf;
        {
            union { short8 v; unsigned d[4]; } f;
            f.v = zero8;
            if (hi5 == 0) {
                f.d[0] = cvtpk(xr[0], xr[1]);
                f.d[1] = cvtpk(xr[2], 1.0f);
            }
            xf = f.v;
        }
        if (it + 1 < GITER && hi5 == 0) {
            const float* xp = xg + ((size_t)(g + GSTRIDE)*32 + r31) * 3;
            xr[0] = xp[0]; xr[1] = xp[1]; xr[2] = xp[2];
        }

        // ---- L0: 2 MFMA; pack+swap -> h1f[4] ----
        short8 h1f[4];
#pragma unroll
        for (int ot = 0; ot < 2; ++ot) {
            float16v a = __builtin_amdgcn_mfma_f32_32x32x16_bf16(
                             w0f[ot], xf, zero16, 0, 0, 0);
            packswap(a, h1f[2*ot], h1f[2*ot+1]);
        }

        // ---- L1: 8 MFMA; W1 frags + bias from LDS; pack+swap -> h2f[4] ----
        short8 h2f[4];
#pragma unroll
        for (int ot = 0; ot < 2; ++ot) {
            float16v a;
#pragma unroll
            for (int q = 0; q < 4; ++q) {
                float4v t = *(const float4v*)&B1L[32*ot + 8*q + 4*hi5];
                a[4*q+0] = t[0]; a[4*q+1] = t[1];
                a[4*q+2] = t[2]; a[4*q+3] = t[3];
            }
#pragma unroll
            for (int kt = 0; kt < 4; ++kt) {
                short8 wf = *(const short8*)
                    &W1L[(((2*kt + hi5) << 6) + 32*ot + r31) * 8];
                a = __builtin_amdgcn_mfma_f32_32x32x16_bf16(
                        wf, h1f[kt], a, 0, 0, 0);
            }
            packswap(a, h2f[2*ot], h2f[2*ot+1]);
        }

        // ---- L2: 16 MFMA, W2 frags from W2L ----
        float* outp = feats + (size_t)g * 128;
#pragma unroll 2
        for (int bt = 0; bt < 4; ++bt) {
            float16v a = zero16;
#pragma unroll
            for (int kt = 0; kt < 4; ++kt) {
                short8 wf = *(const short8*)
                    &W2L[(((2*kt + hi5) << 7) + 32*bt + r31) * 8];
                a = __builtin_amdgcn_mfma_f32_32x32x16_bf16(
                        h2f[kt], wf, a, 0, 0, 0);
            }
            float m0 = fmaxf(fmaxf(a[0],  a[1]),  fmaxf(a[2],  a[3]));
            float m1 = fmaxf(fmaxf(a[4],  a[5]),  fmaxf(a[6],  a[7]));
            float m2 = fmaxf(fmaxf(a[8],  a[9]),  fmaxf(a[10], a[11]));
            float m3 = fmaxf(fmaxf(a[12], a[13]), fmaxf(a[14], a[15]));
            float m  = fmaxf(fmaxf(m0, m1), fmaxf(m2, m3));
            m = fmaxf(m, __shfl_xor(m, 32, 64));
            if (l < 32)
                outp[32*bt + r31] = fmaxf(m + b2v[bt], 0.f);
        }
    }
}

extern "C" void kernel_launch(void* const* d_in, const int* in_sizes, int n_in,
                              void* d_out, int out_size, void* d_ws, size_t ws_size,
                              hipStream_t stream)
{
    const float* xg   = (const float*)d_in[0];
    const float* newx = (const float*)d_in[1];
    const float *W[3], *Bb[3], *G[3], *Be[3], *M[3], *V[3];
    for (int ll = 0; ll < 3; ++ll) {
        W[ll]  = (const float*)d_in[2 + 6*ll + 0];
        Bb[ll] = (const float*)d_in[2 + 6*ll + 1];
        G[ll]  = (const float*)d_in[2 + 6*ll + 2];
        Be[ll] = (const float*)d_in[2 + 6*ll + 3];
        M[ll]  = (const float*)d_in[2 + 6*ll + 4];
        V[ll]  = (const float*)d_in[2 + 6*ll + 5];
    }

    float* wsf = (float*)d_ws;

    fold_kernel<<<32, 256, 0, stream>>>(
        W[0], Bb[0], G[0], Be[0], M[0], V[0],
        W[1], Bb[1], G[1], Be[1], M[1], V[1],
        W[2], Bb[2], G[2], Be[2], M[2], V[2], wsf);

    copy_new_x<<<192, 256, 0, stream>>>((const float4*)newx, (float4*)d_out);

    float* feats = (float*)d_out + NEWX_ELEMS;
    sa_mfma_kernel<<<GRID, 256, 0, stream>>>(xg, wsf, feats);
}

// Round 19
// 75.969 us; speedup vs baseline: 2.7750x; 1.0615x over previous
//
#include <hip/hip_runtime.h>
#include <hip/hip_bf16.h>

#define EPS_BN 1e-5f

typedef __attribute__((ext_vector_type(8)))  short short8;    // 8 x bf16
typedef __attribute__((ext_vector_type(4)))  float float4v;
typedef __attribute__((ext_vector_type(16))) float float16v;  // 32x32 acc

constexpr int NEWX_ELEMS = 196608;    // B*P*3
constexpr int GRID       = 4096;      // 4 waves/block, GITER groups/wave
constexpr int GITER      = 4;
constexpr int GSTRIDE    = GRID * 4;

constexpr int W0F = 0;      // f32[192]  W0' (64x3)
constexpr int B0F = 192;    // f32[64]
constexpr int B1F = 256;    // f32[64]
constexpr int B2F = 320;    // f32[128]
constexpr int W1B = 1792;   // bytes: ushort[4096]  W1' (64x64) bf16
constexpr int W2B = 10240;  // bytes: ushort[8192]  W2' (128x64) bf16

__device__ __forceinline__ unsigned short f2bf(float x) {
    return __builtin_bit_cast(unsigned short, __float2bfloat16(x));
}
__device__ __forceinline__ unsigned cvtpk(float a, float b) {
    unsigned r;
    asm("v_cvt_pk_bf16_f32 %0, %1, %2" : "=v"(r) : "v"(a), "v"(b));
    return r;
}
// gfx950: vdst.high32 <-> vsrc.low32  (HW-validated R16)
__device__ __forceinline__ void plswap(unsigned &a, unsigned &b) {
    asm("v_permlane32_swap_b32 %0, %1" : "+v"(a), "+v"(b));
}

__global__ void fold_kernel(
    const float* w0, const float* b0, const float* g0,
    const float* be0, const float* m0, const float* v0,
    const float* w1, const float* b1, const float* g1,
    const float* be1, const float* m1, const float* v1,
    const float* w2, const float* b2, const float* g2,
    const float* be2, const float* m2, const float* v2,
    float* __restrict__ ws)
{
    const int tg = blockIdx.x * 256 + threadIdx.x;   // 0..8191
    ushort* w1b = (ushort*)((char*)ws + W1B);
    ushort* w2b = (ushort*)((char*)ws + W2B);
    if (tg < 64) {
        float s0 = g0[tg] * rsqrtf(v0[tg] + EPS_BN);
        ws[B0F + tg] = (b0[tg] - m0[tg]) * s0 + be0[tg];
        ws[W0F + tg*3 + 0] = w0[tg*3 + 0] * s0;
        ws[W0F + tg*3 + 1] = w0[tg*3 + 1] * s0;
        ws[W0F + tg*3 + 2] = w0[tg*3 + 2] * s0;
        float s1 = g1[tg] * rsqrtf(v1[tg] + EPS_BN);
        ws[B1F + tg] = (b1[tg] - m1[tg]) * s1 + be1[tg];
    }
    if (tg < 128) {
        float s2 = g2[tg] * rsqrtf(v2[tg] + EPS_BN);
        ws[B2F + tg] = (b2[tg] - m2[tg]) * s2 + be2[tg];
    }
    if (tg < 4096) {
        int o = tg >> 6;
        float s = g1[o] * rsqrtf(v1[o] + EPS_BN);
        w1b[tg] = f2bf(w1[tg] * s);
    }
    if (tg < 8192) {
        int o = tg >> 6;
        float s = g2[o] * rsqrtf(v2[o] + EPS_BN);
        w2b[tg] = f2bf(w2[tg] * s);
    }
}

__global__ void copy_new_x(const float4* __restrict__ in, float4* __restrict__ out)
{
    int i = blockIdx.x * 256 + threadIdx.x;   // < 49,152
    out[i] = in[i];
}

// R18 structure (all-register chain; W1/B1/W2 in LDS) + launch_bounds(256,2):
// R18's no-bound build let the allocator squeeze to VGPR=56 and burn ~30% of
// issue on v_accvgpr copies (VALUBusy 70, MfmaUtil 29 -> issue-port
// saturated with overhead). The (256,2) bound (cap 256) makes it allocate
// the natural ~80-reg live set cleanly (R17 evidence), while LDS (25KB) and
// regs still allow 5-6 waves/SIMD of real occupancy.
__global__ __launch_bounds__(256, 2) void sa_mfma_kernel(
    const float* __restrict__ xg,
    const float* __restrict__ wsf,
    float* __restrict__ feats)
{
    __shared__ __align__(16) ushort W2L[8192];   // 16KB: granule[c 0..7][o 0..127]
    __shared__ __align__(16) ushort W1L[4096];   // 8KB:  granule[c 0..7][o 0..63]
    __shared__ __align__(16) float  B1L[64];     // 256B

    const int tid = threadIdx.x;
    const int w   = tid >> 6;
    const int l   = tid & 63;
    const int r31 = l & 31;
    const int hi5 = l >> 5;

    const ushort* w1b = (const ushort*)((const char*)wsf + W1B);
    const ushort* w2b = (const ushort*)((const char*)wsf + W2B);

    // stage W2' (1024 granules): src gi=(o*8+c) -> dst (c<<7)|o
    {
        const uint4* src = (const uint4*)w2b;
        uint4* dst = (uint4*)W2L;
        for (int gi = tid; gi < 1024; gi += 256)
            dst[((gi & 7) << 7) | (gi >> 3)] = src[gi];
    }
    // stage W1' (512 granules): src gi=(o*8+c) -> dst (c<<6)|o
    {
        const uint4* src = (const uint4*)w1b;
        uint4* dst = (uint4*)W1L;
        for (int gi = tid; gi < 512; gi += 256)
            dst[((gi & 7) << 6) | (gi >> 3)] = src[gi];
    }
    if (tid < 64) B1L[tid] = wsf[B1F + tid];

    const short8 zero8 = {0,0,0,0,0,0,0,0};
    float16v zero16;
#pragma unroll
    for (int i = 0; i < 16; ++i) zero16[i] = 0.f;

    // ---- remaining hoisted weights (small): w0f 8 regs, b2v 4 regs ----
    short8 w0f[2];
#pragma unroll
    for (int ot = 0; ot < 2; ++ot) {
        union { short8 v; unsigned d[4]; } f;
        f.v = zero8;
        if (hi5 == 0) {
            int o = r31 + 32*ot;
            f.d[0] = cvtpk(wsf[W0F + o*3 + 0], wsf[W0F + o*3 + 1]);
            f.d[1] = cvtpk(wsf[W0F + o*3 + 2], wsf[B0F + o]);
        }
        w0f[ot] = f.v;
    }
    float b2v[4];
#pragma unroll
    for (int bt = 0; bt < 4; ++bt)
        b2v[bt] = wsf[B2F + 32*bt + r31];

    __syncthreads();   // W2L/W1L/B1L ready

    const int wid = blockIdx.x * 4 + w;

    // pack+swap: acc layout -> next-layer fragment pair (validated R16)
    auto packswap = [&](const float16v &a, short8 &lo, short8 &hi) {
        unsigned p[8];
#pragma unroll
        for (int q = 0; q < 4; ++q) {
            p[2*q]   = cvtpk(fmaxf(a[4*q+0], 0.f), fmaxf(a[4*q+1], 0.f));
            p[2*q+1] = cvtpk(fmaxf(a[4*q+2], 0.f), fmaxf(a[4*q+3], 0.f));
        }
        union { short8 v; unsigned d[4]; } f0, f1;
        unsigned A = p[0], B = p[2];  plswap(A, B);
        f0.d[0] = A; f0.d[2] = B;
        unsigned C = p[1], D = p[3];  plswap(C, D);
        f0.d[1] = C; f0.d[3] = D;
        unsigned E = p[4], F = p[6];  plswap(E, F);
        f1.d[0] = E; f1.d[2] = F;
        unsigned G = p[5], Hh = p[7]; plswap(G, Hh);
        f1.d[1] = G; f1.d[3] = Hh;
        lo = f0.v; hi = f1.v;
    };

    float xr[3];
    if (hi5 == 0) {
        const float* xp = xg + ((size_t)wid*32 + r31) * 3;
        xr[0] = xp[0]; xr[1] = xp[1]; xr[2] = xp[2];
    }

#pragma unroll 1
    for (int it = 0; it < GITER; ++it) {
        const int g = wid + it * GSTRIDE;

        // x fragment (col = sample r31, k<4 = {x0,x1,x2,1}, hi5==0 half)
        short8 xf;
        {
            union { short8 v; unsigned d[4]; } f;
            f.v = zero8;
            if (hi5 == 0) {
                f.d[0] = cvtpk(xr[0], xr[1]);
                f.d[1] = cvtpk(xr[2], 1.0f);
            }
            xf = f.v;
        }
        if (it + 1 < GITER && hi5 == 0) {
            const float* xp = xg + ((size_t)(g + GSTRIDE)*32 + r31) * 3;
            xr[0] = xp[0]; xr[1] = xp[1]; xr[2] = xp[2];
        }

        // ---- L0: 2 MFMA; pack+swap -> h1f[4] ----
        short8 h1f[4];
#pragma unroll
        for (int ot = 0; ot < 2; ++ot) {
            float16v a = __builtin_amdgcn_mfma_f32_32x32x16_bf16(
                             w0f[ot], xf, zero16, 0, 0, 0);
            packswap(a, h1f[2*ot], h1f[2*ot+1]);
        }

        // ---- L1: 8 MFMA; W1 frags + bias from LDS; pack+swap -> h2f[4] ----
        short8 h2f[4];
#pragma unroll
        for (int ot = 0; ot < 2; ++ot) {
            float16v a;
#pragma unroll
            for (int q = 0; q < 4; ++q) {
                float4v t = *(const float4v*)&B1L[32*ot + 8*q + 4*hi5];
                a[4*q+0] = t[0]; a[4*q+1] = t[1];
                a[4*q+2] = t[2]; a[4*q+3] = t[3];
            }
#pragma unroll
            for (int kt = 0; kt < 4; ++kt) {
                short8 wf = *(const short8*)
                    &W1L[(((2*kt + hi5) << 6) + 32*ot + r31) * 8];
                a = __builtin_amdgcn_mfma_f32_32x32x16_bf16(
                        wf, h1f[kt], a, 0, 0, 0);
            }
            packswap(a, h2f[2*ot], h2f[2*ot+1]);
        }

        // ---- L2: 16 MFMA, W2 frags from W2L ----
        float* outp = feats + (size_t)g * 128;
#pragma unroll 2
        for (int bt = 0; bt < 4; ++bt) {
            float16v a = zero16;
#pragma unroll
            for (int kt = 0; kt < 4; ++kt) {
                short8 wf = *(const short8*)
                    &W2L[(((2*kt + hi5) << 7) + 32*bt + r31) * 8];
                a = __builtin_amdgcn_mfma_f32_32x32x16_bf16(
                        h2f[kt], wf, a, 0, 0, 0);
            }
            float m0 = fmaxf(fmaxf(a[0],  a[1]),  fmaxf(a[2],  a[3]));
            float m1 = fmaxf(fmaxf(a[4],  a[5]),  fmaxf(a[6],  a[7]));
            float m2 = fmaxf(fmaxf(a[8],  a[9]),  fmaxf(a[10], a[11]));
            float m3 = fmaxf(fmaxf(a[12], a[13]), fmaxf(a[14], a[15]));
            float m  = fmaxf(fmaxf(m0, m1), fmaxf(m2, m3));
            m = fmaxf(m, __shfl_xor(m, 32, 64));
            if (l < 32)
                outp[32*bt + r31] = fmaxf(m + b2v[bt], 0.f);
        }
    }
}

extern "C" void kernel_launch(void* const* d_in, const int* in_sizes, int n_in,
                              void* d_out, int out_size, void* d_ws, size_t ws_size,
                              hipStream_t stream)
{
    const float* xg   = (const float*)d_in[0];
    const float* newx = (const float*)d_in[1];
    const float *W[3], *Bb[3], *G[3], *Be[3], *M[3], *V[3];
    for (int ll = 0; ll < 3; ++ll) {
        W[ll]  = (const float*)d_in[2 + 6*ll + 0];
        Bb[ll] = (const float*)d_in[2 + 6*ll + 1];
        G[ll]  = (const float*)d_in[2 + 6*ll + 2];
        Be[ll] = (const float*)d_in[2 + 6*ll + 3];
        M[ll]  = (const float*)d_in[2 + 6*ll + 4];
        V[ll]  = (const float*)d_in[2 + 6*ll + 5];
    }

    float* wsf = (float*)d_ws;

    fold_kernel<<<32, 256, 0, stream>>>(
        W[0], Bb[0], G[0], Be[0], M[0], V[0],
        W[1], Bb[1], G[1], Be[1], M[1], V[1],
        W[2], Bb[2], G[2], Be[2], M[2], V[2], wsf);

    copy_new_x<<<192, 256, 0, stream>>>((const float4*)newx, (float4*)d_out);

    float* feats = (float*)d_out + NEWX_ELEMS;
    sa_mfma_kernel<<<GRID, 256, 0, stream>>>(xg, wsf, feats);
}

// Round 20
// 71.684 us; speedup vs baseline: 2.9409x; 1.0598x over previous
//
#include <hip/hip_runtime.h>
#include <hip/hip_bf16.h>

#define EPS_BN 1e-5f

typedef __attribute__((ext_vector_type(8)))  short short8;    // 8 x bf16
typedef __attribute__((ext_vector_type(4)))  float float4v;
typedef __attribute__((ext_vector_type(16))) float float16v;  // 32x32 acc

constexpr int NEWX_ELEMS = 196608;    // B*P*3
constexpr int GRID       = 2048;      // 4 waves/block, GITER groups/wave
constexpr int GITER      = 8;
constexpr int GSTRIDE    = GRID * 4;

constexpr int W0F = 0;      // f32[192]  W0' (64x3)
constexpr int B0F = 192;    // f32[64]
constexpr int B1F = 256;    // f32[64]
constexpr int B2F = 320;    // f32[128]
constexpr int W1B = 1792;   // bytes: ushort[4096]  W1' (64x64) bf16
constexpr int W2B = 10240;  // bytes: ushort[8192]  W2' (128x64) bf16

__device__ __forceinline__ unsigned short f2bf(float x) {
    return __builtin_bit_cast(unsigned short, __float2bfloat16(x));
}
__device__ __forceinline__ unsigned cvtpk(float a, float b) {
    unsigned r;
    asm("v_cvt_pk_bf16_f32 %0, %1, %2" : "=v"(r) : "v"(a), "v"(b));
    return r;
}
// gfx950: vdst.high32 <-> vsrc.low32  (HW-validated R16)
__device__ __forceinline__ void plswap(unsigned &a, unsigned &b) {
    asm("v_permlane32_swap_b32 %0, %1" : "+v"(a), "+v"(b));
}

__global__ void fold_kernel(
    const float* w0, const float* b0, const float* g0,
    const float* be0, const float* m0, const float* v0,
    const float* w1, const float* b1, const float* g1,
    const float* be1, const float* m1, const float* v1,
    const float* w2, const float* b2, const float* g2,
    const float* be2, const float* m2, const float* v2,
    float* __restrict__ ws)
{
    const int tg = blockIdx.x * 256 + threadIdx.x;   // 0..8191
    ushort* w1b = (ushort*)((char*)ws + W1B);
    ushort* w2b = (ushort*)((char*)ws + W2B);
    if (tg < 64) {
        float s0 = g0[tg] * rsqrtf(v0[tg] + EPS_BN);
        ws[B0F + tg] = (b0[tg] - m0[tg]) * s0 + be0[tg];
        ws[W0F + tg*3 + 0] = w0[tg*3 + 0] * s0;
        ws[W0F + tg*3 + 1] = w0[tg*3 + 1] * s0;
        ws[W0F + tg*3 + 2] = w0[tg*3 + 2] * s0;
        float s1 = g1[tg] * rsqrtf(v1[tg] + EPS_BN);
        ws[B1F + tg] = (b1[tg] - m1[tg]) * s1 + be1[tg];
    }
    if (tg < 128) {
        float s2 = g2[tg] * rsqrtf(v2[tg] + EPS_BN);
        ws[B2F + tg] = (b2[tg] - m2[tg]) * s2 + be2[tg];
    }
    if (tg < 4096) {
        int o = tg >> 6;
        float s = g1[o] * rsqrtf(v1[o] + EPS_BN);
        w1b[tg] = f2bf(w1[tg] * s);
    }
    if (tg < 8192) {
        int o = tg >> 6;
        float s = g2[o] * rsqrtf(v2[o] + EPS_BN);
        w2b[tg] = f2bf(w2[tg] * s);
    }
}

__global__ void copy_new_x(const float4* __restrict__ in, float4* __restrict__ out)
{
    int i = blockIdx.x * 256 + threadIdx.x;   // < 49,152
    out[i] = in[i];
}

// R19 structure (all-register chain; W1/B1/W2 in LDS; launch_bounds(256,2))
// with the last cheap levers: GITER=8 halves the per-block prologue
// (staging + weight loads), and the epilogue max is a sequential fmax chain
// that clang fuses into v_max3_f32 (15 -> ~8 ops per bt).
__global__ __launch_bounds__(256, 2) void sa_mfma_kernel(
    const float* __restrict__ xg,
    const float* __restrict__ wsf,
    float* __restrict__ feats)
{
    __shared__ __align__(16) ushort W2L[8192];   // 16KB: granule[c 0..7][o 0..127]
    __shared__ __align__(16) ushort W1L[4096];   // 8KB:  granule[c 0..7][o 0..63]
    __shared__ __align__(16) float  B1L[64];     // 256B

    const int tid = threadIdx.x;
    const int w   = tid >> 6;
    const int l   = tid & 63;
    const int r31 = l & 31;
    const int hi5 = l >> 5;

    const ushort* w1b = (const ushort*)((const char*)wsf + W1B);
    const ushort* w2b = (const ushort*)((const char*)wsf + W2B);

    // stage W2' (1024 granules): src gi=(o*8+c) -> dst (c<<7)|o
    {
        const uint4* src = (const uint4*)w2b;
        uint4* dst = (uint4*)W2L;
        for (int gi = tid; gi < 1024; gi += 256)
            dst[((gi & 7) << 7) | (gi >> 3)] = src[gi];
    }
    // stage W1' (512 granules): src gi=(o*8+c) -> dst (c<<6)|o
    {
        const uint4* src = (const uint4*)w1b;
        uint4* dst = (uint4*)W1L;
        for (int gi = tid; gi < 512; gi += 256)
            dst[((gi & 7) << 6) | (gi >> 3)] = src[gi];
    }
    if (tid < 64) B1L[tid] = wsf[B1F + tid];

    const short8 zero8 = {0,0,0,0,0,0,0,0};
    float16v zero16;
#pragma unroll
    for (int i = 0; i < 16; ++i) zero16[i] = 0.f;

    // ---- remaining hoisted weights (small): w0f 8 regs, b2v 4 regs ----
    short8 w0f[2];
#pragma unroll
    for (int ot = 0; ot < 2; ++ot) {
        union { short8 v; unsigned d[4]; } f;
        f.v = zero8;
        if (hi5 == 0) {
            int o = r31 + 32*ot;
            f.d[0] = cvtpk(wsf[W0F + o*3 + 0], wsf[W0F + o*3 + 1]);
            f.d[1] = cvtpk(wsf[W0F + o*3 + 2], wsf[B0F + o]);
        }
        w0f[ot] = f.v;
    }
    float b2v[4];
#pragma unroll
    for (int bt = 0; bt < 4; ++bt)
        b2v[bt] = wsf[B2F + 32*bt + r31];

    __syncthreads();   // W2L/W1L/B1L ready

    const int wid = blockIdx.x * 4 + w;

    // pack+swap: acc layout -> next-layer fragment pair (validated R16)
    auto packswap = [&](const float16v &a, short8 &lo, short8 &hi) {
        unsigned p[8];
#pragma unroll
        for (int q = 0; q < 4; ++q) {
            p[2*q]   = cvtpk(fmaxf(a[4*q+0], 0.f), fmaxf(a[4*q+1], 0.f));
            p[2*q+1] = cvtpk(fmaxf(a[4*q+2], 0.f), fmaxf(a[4*q+3], 0.f));
        }
        union { short8 v; unsigned d[4]; } f0, f1;
        unsigned A = p[0], B = p[2];  plswap(A, B);
        f0.d[0] = A; f0.d[2] = B;
        unsigned C = p[1], D = p[3];  plswap(C, D);
        f0.d[1] = C; f0.d[3] = D;
        unsigned E = p[4], F = p[6];  plswap(E, F);
        f1.d[0] = E; f1.d[2] = F;
        unsigned G = p[5], Hh = p[7]; plswap(G, Hh);
        f1.d[1] = G; f1.d[3] = Hh;
        lo = f0.v; hi = f1.v;
    };

    float xr[3];
    if (hi5 == 0) {
        const float* xp = xg + ((size_t)wid*32 + r31) * 3;
        xr[0] = xp[0]; xr[1] = xp[1]; xr[2] = xp[2];
    }

#pragma unroll 1
    for (int it = 0; it < GITER; ++it) {
        const int g = wid + it * GSTRIDE;

        // x fragment (col = sample r31, k<4 = {x0,x1,x2,1}, hi5==0 half)
        short8 xf;
        {
            union { short8 v; unsigned d[4]; } f;
            f.v = zero8;
            if (hi5 == 0) {
                f.d[0] = cvtpk(xr[0], xr[1]);
                f.d[1] = cvtpk(xr[2], 1.0f);
            }
            xf = f.v;
        }
        if (it + 1 < GITER && hi5 == 0) {
            const float* xp = xg + ((size_t)(g + GSTRIDE)*32 + r31) * 3;
            xr[0] = xp[0]; xr[1] = xp[1]; xr[2] = xp[2];
        }

        // ---- L0: 2 MFMA; pack+swap -> h1f[4] ----
        short8 h1f[4];
#pragma unroll
        for (int ot = 0; ot < 2; ++ot) {
            float16v a = __builtin_amdgcn_mfma_f32_32x32x16_bf16(
                             w0f[ot], xf, zero16, 0, 0, 0);
            packswap(a, h1f[2*ot], h1f[2*ot+1]);
        }

        // ---- L1: 8 MFMA; W1 frags + bias from LDS; pack+swap -> h2f[4] ----
        short8 h2f[4];
#pragma unroll
        for (int ot = 0; ot < 2; ++ot) {
            float16v a;
#pragma unroll
            for (int q = 0; q < 4; ++q) {
                float4v t = *(const float4v*)&B1L[32*ot + 8*q + 4*hi5];
                a[4*q+0] = t[0]; a[4*q+1] = t[1];
                a[4*q+2] = t[2]; a[4*q+3] = t[3];
            }
#pragma unroll
            for (int kt = 0; kt < 4; ++kt) {
                short8 wf = *(const short8*)
                    &W1L[(((2*kt + hi5) << 6) + 32*ot + r31) * 8];
                a = __builtin_amdgcn_mfma_f32_32x32x16_bf16(
                        wf, h1f[kt], a, 0, 0, 0);
            }
            packswap(a, h2f[2*ot], h2f[2*ot+1]);
        }

        // ---- L2: 16 MFMA, W2 frags from W2L; max3-chain epilogue ----
        float* outp = feats + (size_t)g * 128;
#pragma unroll 2
        for (int bt = 0; bt < 4; ++bt) {
            float16v a = zero16;
#pragma unroll
            for (int kt = 0; kt < 4; ++kt) {
                short8 wf = *(const short8*)
                    &W2L[(((2*kt + hi5) << 7) + 32*bt + r31) * 8];
                a = __builtin_amdgcn_mfma_f32_32x32x16_bf16(
                        h2f[kt], wf, a, 0, 0, 0);
            }
            float m = a[0];
#pragma unroll
            for (int i = 1; i < 16; ++i)
                m = fmaxf(m, a[i]);          // clang fuses pairs -> v_max3_f32
            m = fmaxf(m, __shfl_xor(m, 32, 64));
            if (l < 32)
                outp[32*bt + r31] = fmaxf(m + b2v[bt], 0.f);
        }
    }
}

extern "C" void kernel_launch(void* const* d_in, const int* in_sizes, int n_in,
                              void* d_out, int out_size, void* d_ws, size_t ws_size,
                              hipStream_t stream)
{
    const float* xg   = (const float*)d_in[0];
    const float* newx = (const float*)d_in[1];
    const float *W[3], *Bb[3], *G[3], *Be[3], *M[3], *V[3];
    for (int ll = 0; ll < 3; ++ll) {
        W[ll]  = (const float*)d_in[2 + 6*ll + 0];
        Bb[ll] = (const float*)d_in[2 + 6*ll + 1];
        G[ll]  = (const float*)d_in[2 + 6*ll + 2];
        Be[ll] = (const float*)d_in[2 + 6*ll + 3];
        M[ll]  = (const float*)d_in[2 + 6*ll + 4];
        V[ll]  = (const float*)d_in[2 + 6*ll + 5];
    }

    float* wsf = (float*)d_ws;

    fold_kernel<<<32, 256, 0, stream>>>(
        W[0], Bb[0], G[0], Be[0], M[0], V[0],
        W[1], Bb[1], G[1], Be[1], M[1], V[1],
        W[2], Bb[2], G[2], Be[2], M[2], V[2], wsf);

    copy_new_x<<<192, 256, 0, stream>>>((const float4*)newx, (float4*)d_out);

    float* feats = (float*)d_out + NEWX_ELEMS;
    sa_mfma_kernel<<<GRID, 256, 0, stream>>>(xg, wsf, feats);
}